// Round 5
// baseline (180.355 us; speedup 1.0000x reference)
//
#include <hip/hip_runtime.h>

// Adaptive_Node_Scale_GCN — MFMA v4 (v3 structure, v2-proven numerics; no inline asm).
// Y[d,n] = sum_{t=0..6} W_t,d · X_{d,n} · M_{t,d}^T,  M ∈ {I, A0, A0², A1, A1², P_d, P_d²}
// M B-fragments read DIRECTLY from global (plain row-major bf16, L2-hot): no M LDS
// staging, no M barriers. kh looped in-block (X staged once). LDS = 32KB: X-stage
// region overlaid by the Z bounce buffer after Xf registers are loaded.

namespace {

constexpr int Kn = 128;
constexpr int En = 10;

typedef __attribute__((ext_vector_type(8))) short short8;
typedef __attribute__((ext_vector_type(4))) float f32x4;

__device__ inline unsigned short f2bf(float f) {
    unsigned x = __float_as_uint(f);
    return (unsigned short)((x + 0x7FFFu + ((x >> 16) & 1u)) >> 16);
}
__device__ inline unsigned pack2(float lo, float hi) {
    return (unsigned)f2bf(lo) | ((unsigned)f2bf(hi) << 16);
}

// ---------------- precompute 1: fp32 mats ----------------
// fp32 slots: 0:A0 2:A1 4..7:P_d
__global__ __launch_bounds__(256) void build_adj(
    const float* __restrict__ supports,
    const float* __restrict__ nv1,
    const float* __restrict__ nv2,
    const float* __restrict__ impW,
    const float* __restrict__ impB,
    float* __restrict__ mats)
{
    const int tid = threadIdx.x;
    const int blk = blockIdx.x;
    if (blk < 2) {
        const float* A = supports + blk * Kn * Kn;
        float* dst = mats + (blk * 2) * Kn * Kn;   // slot 0 / slot 2
        for (int i = tid; i < Kn * Kn; i += 256) dst[i] = A[i];
        return;
    }
    const int d = blk - 2;
    __shared__ float nv1m[Kn * En];
    __shared__ float nv2s[En * Kn];
    for (int i = tid; i < Kn * En; i += 256) nv1m[i] = nv1[d * Kn * En + i];
    for (int i = tid; i < En * Kn; i += 256) nv2s[i] = nv2[d * En * Kn + i];
    __syncthreads();
    float impv[5];
    #pragma unroll
    for (int r = 0; r < 5; ++r) {
        const int idx = tid + r * 256;
        const int j = idx / En, e = idx - j * En;
        float acc = impB[j];
        for (int kk = 0; kk < Kn; ++kk)
            acc += impW[j * Kn + kk] * nv1m[kk * En + e];
        impv[r] = acc;
    }
    __syncthreads();
    #pragma unroll
    for (int r = 0; r < 5; ++r) nv1m[tid + r * 256] *= impv[r];
    __syncthreads();
    if (tid < Kn) {
        const int k = tid;
        float a[En];
        #pragma unroll
        for (int e = 0; e < En; ++e) a[e] = nv1m[k * En + e];
        float mx = 0.f;
        for (int j = 0; j < Kn; ++j) {
            float s = 0.f;
            #pragma unroll
            for (int e = 0; e < En; ++e) s += a[e] * nv2s[e * Kn + j];
            mx = fmaxf(mx, s);
        }
        float sum = 0.f;
        for (int j = 0; j < Kn; ++j) {
            float s = 0.f;
            #pragma unroll
            for (int e = 0; e < En; ++e) s += a[e] * nv2s[e * Kn + j];
            s = fmaxf(s, 0.f);
            sum += expf(s - mx);
        }
        const float inv = 1.f / sum;
        float* dst = mats + (4 + d) * Kn * Kn;
        for (int j = 0; j < Kn; ++j) {
            float s = 0.f;
            #pragma unroll
            for (int e = 0; e < En; ++e) s += a[e] * nv2s[e * Kn + j];
            s = fmaxf(s, 0.f);
            dst[k * Kn + j] = expf(s - mx) * inv;   // P[k][j], row-major
        }
    }
}

// ---------------- precompute 2: squares + bf16 stream (merged) ----------------
// wbm slots (plain row-major M[k][v] bf16):
//   0:I 1:A0 2:A0² 3:A1 4:A1² 5+2d:P_d 6+2d:P²_d
__global__ __launch_bounds__(256) void square_cvt(
    const float* __restrict__ fm, unsigned short* __restrict__ wbm)
{
    const int tid = threadIdx.x;
    if (blockIdx.x < 96) {
        // square: M²[v][k] = sum_u M[v][u] M[u][k], write bf16
        __shared__ float S[Kn * Kn];
        const int m = blockIdx.x >> 4, strip = blockIdx.x & 15;
        const int src = (m == 0) ? 0 : (m == 1) ? 2 : (2 + m);     // fp32 slot
        const int dst = (m == 0) ? 2 : (m == 1) ? 4 : (2 + 2 * m); // wbm slot
        const float* s = fm + src * Kn * Kn;
        unsigned short* o = wbm + dst * Kn * Kn;
        for (int i = tid; i < Kn * Kn; i += 256) S[i] = s[i];
        __syncthreads();
        const int v = strip * 8 + (tid >> 5);
        const int k0 = (tid & 31) * 4;
        float acc0 = 0.f, acc1 = 0.f, acc2 = 0.f, acc3 = 0.f;
        for (int u0 = 0; u0 < Kn; u0 += 4) {
            const float4 av = *reinterpret_cast<const float4*>(&S[v * Kn + u0]);
            const float a[4] = {av.x, av.y, av.z, av.w};
            #pragma unroll
            for (int j = 0; j < 4; ++j) {
                const float4 m4 = *reinterpret_cast<const float4*>(&S[(u0 + j) * Kn + k0]);
                acc0 += a[j] * m4.x; acc1 += a[j] * m4.y;
                acc2 += a[j] * m4.z; acc3 += a[j] * m4.w;
            }
        }
        uint2 r;
        r.x = pack2(acc0, acc1);
        r.y = pack2(acc2, acc3);
        *reinterpret_cast<uint2*>(&o[v * Kn + k0]) = r;
    } else {
        // copy/convert non-squared slots
        const int s = blockIdx.x - 96;  // 0..6
        const int wslot = (s == 0) ? 0 : (s == 1) ? 1 : (s == 2) ? 3 : (5 + 2 * (s - 3));
        const int fsrc  = (s == 0) ? -1 : (s == 1) ? 0 : (s == 2) ? 2 : (4 + (s - 3));
        for (int i = tid; i < Kn * Kn; i += 256) {
            const int k = i >> 7, v = i & 127;
            const float val = (fsrc < 0) ? ((k == v) ? 1.f : 0.f) : fm[fsrc * 16384 + i];
            wbm[wslot * 16384 + i] = f2bf(val);
        }
    }
}

// ---------------- fused MFMA kernel ----------------
// block = (d, b, 8 l's); kh looped. LDS 32KB: X-stage rows (n*16+c)×256B,
// overlaid by Z [n][kp 64][tp 2][c 16] bf16 (wave-disjoint slots, barrier-guarded).
__global__ __launch_bounds__(256, 3) void fused_mfma(
    const float* __restrict__ x,
    const unsigned short* __restrict__ wbm,
    const float* __restrict__ mlpW,   // (4,16,112)
    const float* __restrict__ mlpB,   // (4,16)
    float* __restrict__ out)
{
    __shared__ __align__(16) char lds[32768];
    const int tid = threadIdx.x;
    const int lane = tid & 63, lr = lane & 15, lg = lane >> 4;
    const int wid = tid >> 6, wr = wid >> 1, wk = wid & 1;

    const unsigned u = blockIdx.x;                 // 0..1023
    const unsigned pid = (u & 7) * 128 + (u >> 3); // XCD-chunked
    const int lt = pid & 15;
    const int b  = (pid >> 4) & 15;
    const int d  = (int)(pid >> 8);
    const int l0 = lt * 8;

    // ---- stage X -> [(n*16+c)][v] bf16, swizzled: byte = row*256 + (2v ^ ((c&7)<<4))
    {
        const int cg = tid >> 5;      // 0..7
        const int vi = tid & 31;      // 0..31 -> full 32-bank spread
        #pragma unroll
        for (int cc = 0; cc < 2; ++cc) {
            const int c = cc * 8 + cg;
            const float* xb = x + (size_t)b * 1048576 + d * 16384 + l0 + c * 65536;
            const int swz = (c & 7) << 4;
            #pragma unroll
            for (int vp = 0; vp < 2; ++vp) {
                const int vpair = vp * 32 + vi;        // 0..63
                const int v = vpair * 2;
                const float* p0 = xb + v * 128;
                const float4 a0 = *reinterpret_cast<const float4*>(p0);
                const float4 a1 = *reinterpret_cast<const float4*>(p0 + 4);
                const float4 b0 = *reinterpret_cast<const float4*>(p0 + 128);
                const float4 b1 = *reinterpret_cast<const float4*>(p0 + 132);
                const float av[8] = {a0.x, a0.y, a0.z, a0.w, a1.x, a1.y, a1.z, a1.w};
                const float bv[8] = {b0.x, b0.y, b0.z, b0.w, b1.x, b1.y, b1.z, b1.w};
                #pragma unroll
                for (int n = 0; n < 8; ++n)
                    *reinterpret_cast<unsigned*>(
                        lds + (n * 16 + c) * 256 + ((4 * vpair) ^ swz)) = pack2(av[n], bv[n]);
            }
        }
    }

    // ---- W fragments (A-operand of phase B), zero-padded 8th t-slot (v2-proven)
    short8 Wf[4];
    #pragma unroll
    for (int p = 0; p < 4; ++p) {
        short8 w;
        #pragma unroll
        for (int j = 0; j < 8; ++j) {
            const int tc = lg * 8 + j, t = 2 * p + (tc >> 4), c = tc & 15;
            const float wv = (t < 7) ? mlpW[d * 1792 + lr * 112 + t * 16 + c] : 0.f;
            w[j] = (short)f2bf(wv);
        }
        Wf[p] = w;
    }

    __syncthreads();   // X staged

    // ---- X A-fragments -> registers (valid for both kh; X LDS dead after)
    short8 Xf[4][4];
    {
        const int swz = (lr & 7) << 4;
        #pragma unroll
        for (int rti = 0; rti < 4; ++rti) {
            const int base = ((wr * 4 + rti) * 16 + lr) * 256;
            #pragma unroll
            for (int ks = 0; ks < 4; ++ks)
                Xf[rti][ks] = *reinterpret_cast<const short8*>(
                    lds + base + ((ks * 64 + lg * 16) ^ swz));
        }
    }
    __syncthreads();   // all waves done reading X before Z overlay writes

    f32x4 bias;
    #pragma unroll
    for (int r = 0; r < 4; ++r) bias[r] = mlpB[d * 16 + lg * 4 + r];
    const f32x4 zero4 = {0.f, 0.f, 0.f, 0.f};
    float* ob = out + (size_t)b * 1048576 + d * 16384 + l0;

    #pragma unroll 1
    for (int kh2 = 0; kh2 < 2; ++kh2) {
        f32x4 Y[2][4];
        #pragma unroll
        for (int ni = 0; ni < 2; ++ni)
            #pragma unroll
            for (int kt = 0; kt < 4; ++kt) Y[ni][kt] = zero4;

        #pragma unroll
        for (int p = 0; p < 4; ++p) {
            #pragma unroll
            for (int tp = 0; tp < ((p < 3) ? 2 : 1); ++tp) {
                const int tpos = 2 * p + tp;
                const int slot = (tpos < 5) ? tpos : (5 + 2 * d + (tpos - 5));
                // B-fragments of M straight from global (row-major, L2-hot):
                // lane needs M[kp][v], kp = kh2*64 + (wk*2+j)*16 + lr, v = ks*32+lg*8..
                const unsigned short* mb =
                    wbm + slot * 16384 + kh2 * 8192 + wk * 4096 + lr * 128 + lg * 8;
                f32x4 D[4][2];
                #pragma unroll
                for (int rti = 0; rti < 4; ++rti) {
                    D[rti][0] = zero4; D[rti][1] = zero4;
                }
                #pragma unroll
                for (int ks = 0; ks < 4; ++ks) {
                    const short8 Bf0 = *reinterpret_cast<const short8*>(mb + ks * 32);
                    const short8 Bf1 = *reinterpret_cast<const short8*>(mb + 2048 + ks * 32);
                    #pragma unroll
                    for (int rti = 0; rti < 4; ++rti) {
                        D[rti][0] = __builtin_amdgcn_mfma_f32_16x16x32_bf16(
                            Xf[rti][ks], Bf0, D[rti][0], 0, 0, 0);
                        D[rti][1] = __builtin_amdgcn_mfma_f32_16x16x32_bf16(
                            Xf[rti][ks], Bf1, D[rti][1], 0, 0, 0);
                    }
                }
                // write Z[n][kp][tp][c] bf16
                #pragma unroll
                for (int rti = 0; rti < 4; ++rti) {
                    #pragma unroll
                    for (int j = 0; j < 2; ++j) {
                        const int n = wr * 4 + rti;
                        const int kp = (wk * 2 + j) * 16 + lr;
                        uint2 zz;
                        zz.x = pack2(D[rti][j][0], D[rti][j][1]);
                        zz.y = pack2(D[rti][j][2], D[rti][j][3]);
                        *reinterpret_cast<uint2*>(
                            lds + n * 4096 +
                            ((kp * 64 + tp * 32 + lg * 8) ^ ((kp & 7) << 4))) = zz;
                        if (tpos == 6) {
                            // explicitly zero the wave-owned tp=1 slots (defensive:
                            // the matching W upper half is 0, never multiply garbage)
                            const uint2 z0 = {0u, 0u};
                            *reinterpret_cast<uint2*>(
                                lds + n * 4096 +
                                ((kp * 64 + 32 + lg * 8) ^ ((kp & 7) << 4))) = z0;
                        }
                    }
                }
            }
            __syncthreads();   // Z(pair) visible

            // phase B: Y += W_pair · Z
            #pragma unroll
            for (int ni = 0; ni < 2; ++ni) {
                const int n = wid * 2 + ni;
                #pragma unroll
                for (int ktl = 0; ktl < 4; ++ktl) {
                    const int kp = ktl * 16 + lr;
                    const short8 Bfz = *reinterpret_cast<const short8*>(
                        lds + n * 4096 + ((kp * 64 + lg * 16) ^ ((kp & 7) << 4)));
                    Y[ni][ktl] = __builtin_amdgcn_mfma_f32_16x16x32_bf16(
                        Wf[p], Bfz, Y[ni][ktl], 0, 0, 0);
                }
            }
            __syncthreads();   // Z free for next pair / next kh2
        }

        // ---- store this kh: out[b, o, d, kh2*64+kp, l0+n], D rows o = lg*4+r
        #pragma unroll
        for (int ni = 0; ni < 2; ++ni) {
            const int n = wid * 2 + ni;
            #pragma unroll
            for (int ktl = 0; ktl < 4; ++ktl) {
                float* pp = ob + (kh2 * 64 + ktl * 16 + lr) * 128 + n;
                #pragma unroll
                for (int r = 0; r < 4; ++r)
                    pp[(lg * 4 + r) * 65536] = Y[ni][ktl][r] + bias[r];
            }
        }
    }
}

}  // namespace

extern "C" void kernel_launch(void* const* d_in, const int* in_sizes, int n_in,
                              void* d_out, int out_size, void* d_ws, size_t ws_size,
                              hipStream_t stream)
{
    const float* x    = (const float*)d_in[0];
    const float* sup  = (const float*)d_in[1];
    const float* nv1  = (const float*)d_in[2];
    const float* nv2  = (const float*)d_in[3];
    const float* impW = (const float*)d_in[4];
    const float* impB = (const float*)d_in[5];
    const float* mlpW = (const float*)d_in[6];
    const float* mlpB = (const float*)d_in[7];
    float* outp = (float*)d_out;

    float* fm = (float*)d_ws;                                        // fp32 mats
    unsigned short* wbm = (unsigned short*)((char*)d_ws + 786432);   // 13 × 32KB bf16

    build_adj<<<6, 256, 0, stream>>>(sup, nv1, nv2, impW, impB, fm);
    square_cvt<<<103, 256, 0, stream>>>(fm, wbm);
    fused_mfma<<<1024, 256, 0, stream>>>(x, wbm, mlpW, mlpB, outp);
}